// Round 9
// baseline (118.825 us; speedup 1.0000x reference)
//
#include <hip/hip_runtime.h>

#define NPOS 8192
#define NC 64
#define NB 4
#define NSPLIT 4
#define NCHUNK 2048  // 32 tiles of 64, even split, no tail
// q pre-scaled by (1/128)*log2(e) so softmax weight = exp2(mfma output)
#define QSCALE 0.01127105500167846f

typedef __bf16 bf16x8 __attribute__((ext_vector_type(8)));
typedef __bf16 bf16x4 __attribute__((ext_vector_type(4)));
typedef float f32x4 __attribute__((ext_vector_type(4)));

#define EXP2F(x) __builtin_amdgcn_exp2f(x)

static __device__ __forceinline__ unsigned f2bf_u(float x) {
  unsigned u = __float_as_uint(x);
  return (u + 0x7FFFu + ((u >> 16) & 1u)) >> 16;
}
static __device__ __forceinline__ unsigned pack2(float a, float b) {
  return f2bf_u(a) | (f2bf_u(b) << 16);
}

static __device__ __forceinline__ void gload_lds16(const void* gsrc, void* lds_base) {
  __builtin_amdgcn_global_load_lds(
      (const __attribute__((address_space(1))) unsigned int*)gsrc,
      (__attribute__((address_space(3))) unsigned int*)lds_base, 16, 0, 0);
}

// Stage 1: 1x1 conv projections. q,k -> [B][N][C] bf16 (position-major),
// v -> [B][C][N] bf16 + fp32. q additionally scaled by QSCALE.
__global__ __launch_bounds__(256) void proj_kernel(
    const float* __restrict__ xq, const float* __restrict__ xk, const float* __restrict__ xv,
    const float* __restrict__ Wq, const float* __restrict__ bq,
    const float* __restrict__ Wk, const float* __restrict__ bk,
    const float* __restrict__ Wv, const float* __restrict__ bv,
    unsigned short* __restrict__ qT, unsigned short* __restrict__ kT,
    unsigned short* __restrict__ vb, float* __restrict__ vf)
{
  __shared__ float sW[NC * NC];
  __shared__ float sB[NC];
  const int p = blockIdx.z, b = blockIdx.y;
  const int n0 = blockIdx.x * 128;
  const int tid = threadIdx.x;
  const int wv = tid >> 6, l = tid & 63;

  const float* x    = p == 0 ? xq : (p == 1 ? xk : xv);
  const float* W    = p == 0 ? Wq : (p == 1 ? Wk : Wv);
  const float* bias = p == 0 ? bq : (p == 1 ? bk : bv);

  for (int i = tid; i < NC * NC; i += 256) sW[i] = W[i];
  if (tid < NC) sB[tid] = bias[tid];
  __syncthreads();

  const int nb = n0 + 2 * l;
  const float* xb = x + (size_t)b * NC * NPOS + nb;

  float acc[16][2];
#pragma unroll
  for (int oi = 0; oi < 16; ++oi) {
    float bz = sB[16 * wv + oi];
    acc[oi][0] = bz; acc[oi][1] = bz;
  }
  for (int c = 0; c < NC; ++c) {
    const float2 x2 = *(const float2*)(xb + (size_t)c * NPOS);
#pragma unroll
    for (int oi = 0; oi < 16; ++oi) {
      float wgt = sW[(16 * wv + oi) * NC + c];
      acc[oi][0] = fmaf(wgt, x2.x, acc[oi][0]);
      acc[oi][1] = fmaf(wgt, x2.y, acc[oi][1]);
    }
  }

  if (p < 2) {
    const float qs = (p == 0) ? QSCALE : 1.0f;
    unsigned short* dst = (p == 0 ? qT : kT) + (size_t)b * NPOS * NC;
#pragma unroll
    for (int r = 0; r < 2; ++r) {
      uint4 w0, w1;
      w0.x = pack2(qs * acc[0][r],  qs * acc[1][r]);
      w0.y = pack2(qs * acc[2][r],  qs * acc[3][r]);
      w0.z = pack2(qs * acc[4][r],  qs * acc[5][r]);
      w0.w = pack2(qs * acc[6][r],  qs * acc[7][r]);
      w1.x = pack2(qs * acc[8][r],  qs * acc[9][r]);
      w1.y = pack2(qs * acc[10][r], qs * acc[11][r]);
      w1.z = pack2(qs * acc[12][r], qs * acc[13][r]);
      w1.w = pack2(qs * acc[14][r], qs * acc[15][r]);
      unsigned short* rp = dst + (size_t)(nb + r) * NC + 16 * wv;
      *(uint4*)(rp) = w0;
      *(uint4*)(rp + 8) = w1;
    }
  } else {
#pragma unroll
    for (int oi = 0; oi < 16; ++oi) {
      const int o = 16 * wv + oi;
      float2 v2;
      v2.x = acc[oi][0]; v2.y = acc[oi][1];
      *(float2*)(vf + ((size_t)b * NC + o) * NPOS + nb) = v2;
      *(unsigned*)(vb + ((size_t)b * NC + o) * NPOS + nb) = pack2(acc[oi][0], acc[oi][1]);
    }
  }
}

// Stage 2: flash attention partials. Block = 512 threads (8 waves), 256 cols
// (32 cols/wave via dual K-fragment sets). R6 structure + ones-row MFMA
// computing the softmax denominator (no VALU lsum adds, no shuffles).
__global__ __launch_bounds__(512) void attn_partial(
    const unsigned short* __restrict__ qT,
    const unsigned short* __restrict__ kT,
    const unsigned short* __restrict__ vb,
    float* __restrict__ pav, float* __restrict__ plsum)
{
  __shared__ unsigned short qs_[2][64 * 64];   // 8KB each, XOR-swizzled rows
  __shared__ unsigned short vs_[2][64 * 64];
  __shared__ unsigned short pT[8][16][68];     // stride 136B: conflict-free b64 r/w

  const int b = blockIdx.y, z = blockIdx.z;
  const int m0 = blockIdx.x * 256;
  const int tid = threadIdx.x;
  const int w = tid >> 6, l = tid & 63;
  const int lm = l & 15, g = l >> 4;
  const int mA = m0 + 32 * w + lm;       // column set A
  const int mB = mA + 16;                // column set B

  const unsigned short* kbA = kT + (size_t)(b * NPOS + mA) * NC + 8 * g;
  const unsigned short* kbB = kT + (size_t)(b * NPOS + mB) * NC + 8 * g;
  const bf16x8 kb0 = *(const bf16x8*)(kbA);
  const bf16x8 kb1 = *(const bf16x8*)(kbA + 32);
  const bf16x8 kb2 = *(const bf16x8*)(kbB);
  const bf16x8 kb3 = *(const bf16x8*)(kbB + 32);

  const __bf16 one1 = (__bf16)1.0f;
  const bf16x8 vones = {one1, one1, one1, one1, one1, one1, one1, one1};

  const char* qb  = (const char*)(qT + (size_t)b * NPOS * NC);
  const char* vbb = (const char*)(vb + (size_t)b * NC * NPOS);

  // staging geometry: thread t writes 16B at LDS byte t*16 = (row=t>>3, swz col (t&7)*16)
  const int srow = tid >> 3;
  const int slc  = ((tid & 7) * 16) ^ ((srow & 7) << 4);  // inverse-swizzled src col
  const char* qsrc0 = qb + (size_t)srow * 128 + slc;          // + n0*128
  const char* vsrc0 = vbb + (size_t)srow * (NPOS * 2) + slc;  // + n0*2
  const int ldsoff = w * 512;  // shorts; wave-uniform base for global_load_lds

  f32x4 accA[4] = {{0,0,0,0},{0,0,0,0},{0,0,0,0},{0,0,0,0}};
  f32x4 accB[4] = {{0,0,0,0},{0,0,0,0},{0,0,0,0},{0,0,0,0}};
  f32x4 accLA = {0,0,0,0}, accLB = {0,0,0,0};   // ones-row: denominator per col

  const int nbeg = z * NCHUNK;
  const int iters = NCHUNK >> 6;  // 32, even for all z

  // prologue: stage buffer 0
  gload_lds16(qsrc0 + (size_t)nbeg * 128, &qs_[0][ldsoff]);
  gload_lds16(vsrc0 + (size_t)nbeg * 2,   &vs_[0][ldsoff]);

  const int swz = (lm & 7) << 4;  // read-side swizzle

  int cur = 0;
  for (int t = 0; t < iters; ++t) {
    const int n0 = nbeg + 64 * t;
    // barrier A: everyone finished reading buf cur^1 (iter t-1) -> safe to overwrite
    __builtin_amdgcn_s_barrier();
    if (t + 1 < iters) {
      gload_lds16(qsrc0 + (size_t)(n0 + 64) * 128, &qs_[cur ^ 1][ldsoff]);
      gload_lds16(vsrc0 + (size_t)(n0 + 64) * 2,   &vs_[cur ^ 1][ldsoff]);
      asm volatile("s_waitcnt vmcnt(2)" ::: "memory");  // stage(t) done; t+1 in flight
    } else {
      asm volatile("s_waitcnt vmcnt(0)" ::: "memory");
    }
    // barrier B: all waves' stage(t) complete -> tile readable
    __builtin_amdgcn_s_barrier();
    __builtin_amdgcn_sched_barrier(0);

    const unsigned short* qt = qs_[cur];
    const unsigned short* vt = vs_[cur];

    // QK^T for both column sets; q-fragments feed 4 MFMA each
    f32x4 s0[4], s1[4];
    __builtin_amdgcn_s_setprio(1);
#pragma unroll
    for (int sub = 0; sub < 4; ++sub) {
      const int nl = 16 * sub + lm;
      bf16x8 qa0 = *(const bf16x8*)(qt + nl * 64 + (((16 * g) ^ swz) >> 1));
      bf16x8 qa1 = *(const bf16x8*)(qt + nl * 64 + (((64 + 16 * g) ^ swz) >> 1));
      f32x4 za = {0, 0, 0, 0};
      za = __builtin_amdgcn_mfma_f32_16x16x32_bf16(qa0, kb0, za, 0, 0, 0);
      za = __builtin_amdgcn_mfma_f32_16x16x32_bf16(qa1, kb1, za, 0, 0, 0);
      s0[sub] = za;
      f32x4 zb = {0, 0, 0, 0};
      zb = __builtin_amdgcn_mfma_f32_16x16x32_bf16(qa0, kb2, zb, 0, 0, 0);
      zb = __builtin_amdgcn_mfma_f32_16x16x32_bf16(qa1, kb3, zb, 0, 0, 0);
      s1[sub] = zb;
    }
    __builtin_amdgcn_s_setprio(0);

    // ---- softmax A -> pT (no lsum adds; denominator comes from ones-MFMA) ----
#pragma unroll
    for (int sub = 0; sub < 4; ++sub) {
      float p0 = EXP2F(s0[sub][0]);
      float p1 = EXP2F(s0[sub][1]);
      float p2 = EXP2F(s0[sub][2]);
      float p3 = EXP2F(s0[sub][3]);
      bf16x4 pk;
      pk[0] = (__bf16)p0; pk[1] = (__bf16)p1;
      pk[2] = (__bf16)p2; pk[3] = (__bf16)p3;
      *(bf16x4*)&pT[w][lm][16 * sub + 4 * g] = pk;
    }
    // ---- PV A: pb feeds 4 V-MFMA + 1 ones-MFMA; V kept for pass B ----
    bf16x8 va[2][4];
    __builtin_amdgcn_s_setprio(1);
#pragma unroll
    for (int ks = 0; ks < 2; ++ks) {
      bf16x8 pb = *(const bf16x8*)&pT[w][lm][8 * g + 32 * ks];
#pragma unroll
      for (int cs = 0; cs < 4; ++cs) {
        const int vr = 16 * cs + lm;
        va[ks][cs] = *(const bf16x8*)(vt + vr * 64 + (((16 * g + 64 * ks) ^ swz) >> 1));
        accA[cs] = __builtin_amdgcn_mfma_f32_16x16x32_bf16(va[ks][cs], pb, accA[cs], 0, 0, 0);
      }
      accLA = __builtin_amdgcn_mfma_f32_16x16x32_bf16(vones, pb, accLA, 0, 0, 0);
    }
    __builtin_amdgcn_s_setprio(0);

    // ---- softmax B ----
#pragma unroll
    for (int sub = 0; sub < 4; ++sub) {
      float p0 = EXP2F(s1[sub][0]);
      float p1 = EXP2F(s1[sub][1]);
      float p2 = EXP2F(s1[sub][2]);
      float p3 = EXP2F(s1[sub][3]);
      bf16x4 pk;
      pk[0] = (__bf16)p0; pk[1] = (__bf16)p1;
      pk[2] = (__bf16)p2; pk[3] = (__bf16)p3;
      *(bf16x4*)&pT[w][lm][16 * sub + 4 * g] = pk;
    }
    // ---- PV B: reuse va ----
    __builtin_amdgcn_s_setprio(1);
#pragma unroll
    for (int ks = 0; ks < 2; ++ks) {
      bf16x8 pb = *(const bf16x8*)&pT[w][lm][8 * g + 32 * ks];
#pragma unroll
      for (int cs = 0; cs < 4; ++cs) {
        accB[cs] = __builtin_amdgcn_mfma_f32_16x16x32_bf16(va[ks][cs], pb, accB[cs], 0, 0, 0);
      }
      accLB = __builtin_amdgcn_mfma_f32_16x16x32_bf16(vones, pb, accLB, 0, 0, 0);
    }
    __builtin_amdgcn_s_setprio(0);
    cur ^= 1;
  }

  // accL[0] holds the full column-denominator (identical across rows/g)
  if (l < 16) {
    plsum[((size_t)(z * NB + b) << 13) + mA] = accLA[0];
    plsum[((size_t)(z * NB + b) << 13) + mB] = accLB[0];
  }

  float* po = pav + ((size_t)((z * NB + b) * NC) << 13);
#pragma unroll
  for (int cs = 0; cs < 4; ++cs) {
#pragma unroll
    for (int r = 0; r < 4; ++r) {
      const int c = 16 * cs + 4 * g + r;
      po[((size_t)c << 13) + mA] = accA[cs][r];
      po[((size_t)c << 13) + mB] = accB[cs][r];
    }
  }
}

// Stage 3: combine partials, normalize, epilogue.
__global__ __launch_bounds__(256) void reduce_kernel(
    const float* __restrict__ pav, const float* __restrict__ plsum,
    const float* __restrict__ vf, const float* __restrict__ gamma_p,
    float* __restrict__ out)
{
  const size_t base = ((size_t)blockIdx.x * 256 + threadIdx.x) * 4;
  const int m = (int)(base & (NPOS - 1));
  const int bc = (int)(base >> 13);       // b*64 + c
  const int b = bc >> 6;

  float4 s = {0, 0, 0, 0};
  float4 L = {0, 0, 0, 0};
#pragma unroll
  for (int zz = 0; zz < NSPLIT; ++zz) {
    const float4 a = *(const float4*)(pav + (((size_t)(zz * NB * NC + bc)) << 13) + m);
    s.x += a.x; s.y += a.y; s.z += a.z; s.w += a.w;
    const float4 q = *(const float4*)(plsum + (((size_t)(zz * NB + b)) << 13) + m);
    L.x += q.x; L.y += q.y; L.z += q.z; L.w += q.w;
  }
  const float gmv = gamma_p[0];
  const float4 v4 = *(const float4*)(vf + base);
  float4 o;
  o.x = gmv * s.x / L.x + v4.x;
  o.y = gmv * s.y / L.y + v4.y;
  o.z = gmv * s.z / L.z + v4.z;
  o.w = gmv * s.w / L.w + v4.w;
  *(float4*)(out + base) = o;
}

extern "C" void kernel_launch(void* const* d_in, const int* in_sizes, int n_in,
                              void* d_out, int out_size, void* d_ws, size_t ws_size,
                              hipStream_t stream) {
  const float* xq = (const float*)d_in[0];
  const float* xk = (const float*)d_in[1];
  const float* xv = (const float*)d_in[2];
  const float* Wq = (const float*)d_in[3];
  const float* bq = (const float*)d_in[4];
  const float* Wk = (const float*)d_in[5];
  const float* bk = (const float*)d_in[6];
  const float* Wv = (const float*)d_in[7];
  const float* bv = (const float*)d_in[8];
  const float* gm = (const float*)d_in[9];
  float* out = (float*)d_out;

  // ws: qT(4MB) | kT(4MB) | v_bf16(4MB) | v_f32(8MB) | pav(32MB) | plsum(512KB)
  unsigned short* qT   = (unsigned short*)d_ws;
  unsigned short* kT   = qT + (size_t)NB * NPOS * NC;
  unsigned short* vbuf = kT + (size_t)NB * NPOS * NC;
  float* vf    = (float*)(vbuf + (size_t)NB * NPOS * NC);
  float* pav   = vf + (size_t)NB * NC * NPOS;
  float* plsum = pav + (size_t)NSPLIT * NB * NC * NPOS;

  hipLaunchKernelGGL(proj_kernel, dim3(64, 4, 3), dim3(256), 0, stream,
                     xq, xk, xv, Wq, bq, Wk, bk, Wv, bv, qT, kT, vbuf, vf);
  hipLaunchKernelGGL(attn_partial, dim3(NPOS / 256, NB, NSPLIT), dim3(512), 0, stream,
                     qT, kT, vbuf, pav, plsum);
  hipLaunchKernelGGL(reduce_kernel, dim3(2048), dim3(256), 0, stream,
                     pav, plsum, vf, gm, out);
}

// Round 10
// 113.613 us; speedup vs baseline: 1.0459x; 1.0459x over previous
//
#include <hip/hip_runtime.h>

#define NPOS 8192
#define NC 64
#define NB 4
#define NSPLIT 4
#define NCHUNK 2048  // 32 tiles of 64, even split, no tail
// q pre-scaled by (1/128)*log2(e) so softmax weight = exp2(mfma output)
#define QSCALE 0.01127105500167846f

typedef __bf16 bf16x8 __attribute__((ext_vector_type(8)));
typedef __bf16 bf16x4 __attribute__((ext_vector_type(4)));
typedef float f32x4 __attribute__((ext_vector_type(4)));

#define EXP2F(x) __builtin_amdgcn_exp2f(x)

static __device__ __forceinline__ unsigned f2bf_u(float x) {
  unsigned u = __float_as_uint(x);
  return (u + 0x7FFFu + ((u >> 16) & 1u)) >> 16;
}
static __device__ __forceinline__ unsigned pack2(float a, float b) {
  return f2bf_u(a) | (f2bf_u(b) << 16);
}

static __device__ __forceinline__ void gload_lds16(const void* gsrc, void* lds_base) {
  __builtin_amdgcn_global_load_lds(
      (const __attribute__((address_space(1))) unsigned int*)gsrc,
      (__attribute__((address_space(3))) unsigned int*)lds_base, 16, 0, 0);
}

// Stage 1: 1x1 conv projections. q,k -> [B][N][C] bf16 (position-major),
// v -> [B][C][N] bf16 + fp32. q additionally scaled by QSCALE.
__global__ __launch_bounds__(256) void proj_kernel(
    const float* __restrict__ xq, const float* __restrict__ xk, const float* __restrict__ xv,
    const float* __restrict__ Wq, const float* __restrict__ bq,
    const float* __restrict__ Wk, const float* __restrict__ bk,
    const float* __restrict__ Wv, const float* __restrict__ bv,
    unsigned short* __restrict__ qT, unsigned short* __restrict__ kT,
    unsigned short* __restrict__ vb, float* __restrict__ vf)
{
  __shared__ float sW[NC * NC];
  __shared__ float sB[NC];
  const int p = blockIdx.z, b = blockIdx.y;
  const int n0 = blockIdx.x * 128;
  const int tid = threadIdx.x;
  const int wv = tid >> 6, l = tid & 63;

  const float* x    = p == 0 ? xq : (p == 1 ? xk : xv);
  const float* W    = p == 0 ? Wq : (p == 1 ? Wk : Wv);
  const float* bias = p == 0 ? bq : (p == 1 ? bk : bv);

  for (int i = tid; i < NC * NC; i += 256) sW[i] = W[i];
  if (tid < NC) sB[tid] = bias[tid];
  __syncthreads();

  const int nb = n0 + 2 * l;
  const float* xb = x + (size_t)b * NC * NPOS + nb;

  float acc[16][2];
#pragma unroll
  for (int oi = 0; oi < 16; ++oi) {
    float bz = sB[16 * wv + oi];
    acc[oi][0] = bz; acc[oi][1] = bz;
  }
  for (int c = 0; c < NC; ++c) {
    const float2 x2 = *(const float2*)(xb + (size_t)c * NPOS);
#pragma unroll
    for (int oi = 0; oi < 16; ++oi) {
      float wgt = sW[(16 * wv + oi) * NC + c];
      acc[oi][0] = fmaf(wgt, x2.x, acc[oi][0]);
      acc[oi][1] = fmaf(wgt, x2.y, acc[oi][1]);
    }
  }

  if (p < 2) {
    const float qs = (p == 0) ? QSCALE : 1.0f;
    unsigned short* dst = (p == 0 ? qT : kT) + (size_t)b * NPOS * NC;
#pragma unroll
    for (int r = 0; r < 2; ++r) {
      uint4 w0, w1;
      w0.x = pack2(qs * acc[0][r],  qs * acc[1][r]);
      w0.y = pack2(qs * acc[2][r],  qs * acc[3][r]);
      w0.z = pack2(qs * acc[4][r],  qs * acc[5][r]);
      w0.w = pack2(qs * acc[6][r],  qs * acc[7][r]);
      w1.x = pack2(qs * acc[8][r],  qs * acc[9][r]);
      w1.y = pack2(qs * acc[10][r], qs * acc[11][r]);
      w1.z = pack2(qs * acc[12][r], qs * acc[13][r]);
      w1.w = pack2(qs * acc[14][r], qs * acc[15][r]);
      unsigned short* rp = dst + (size_t)(nb + r) * NC + 16 * wv;
      *(uint4*)(rp) = w0;
      *(uint4*)(rp + 8) = w1;
    }
  } else {
#pragma unroll
    for (int oi = 0; oi < 16; ++oi) {
      const int o = 16 * wv + oi;
      float2 v2;
      v2.x = acc[oi][0]; v2.y = acc[oi][1];
      *(float2*)(vf + ((size_t)b * NC + o) * NPOS + nb) = v2;
      *(unsigned*)(vb + ((size_t)b * NC + o) * NPOS + nb) = pack2(acc[oi][0], acc[oi][1]);
    }
  }
}

// Stage 2: flash attention partials. Block = 512 threads (8 waves), 256 cols,
// 32 cols/wave via dual K-fragment sets processed as TWO SEQUENTIAL PASSES
// (register diet: only kb0-3 + acc live across passes). 2-buffer LDS staging,
// counted vmcnt.
__global__ __launch_bounds__(512) void attn_partial(
    const unsigned short* __restrict__ qT,
    const unsigned short* __restrict__ kT,
    const unsigned short* __restrict__ vb,
    float* __restrict__ pav, float* __restrict__ plsum)
{
  __shared__ unsigned short qs_[2][64 * 64];   // 8KB each, XOR-swizzled rows
  __shared__ unsigned short vs_[2][64 * 64];
  __shared__ unsigned short pT[8][16][68];     // stride 136B: conflict-free b64 r/w

  const int b = blockIdx.y, z = blockIdx.z;
  const int m0 = blockIdx.x * 256;
  const int tid = threadIdx.x;
  const int w = tid >> 6, l = tid & 63;
  const int lm = l & 15, g = l >> 4;
  const int mA = m0 + 32 * w + lm;       // column set A
  const int mB = mA + 16;                // column set B

  const unsigned short* kbA = kT + (size_t)(b * NPOS + mA) * NC + 8 * g;
  const unsigned short* kbB = kT + (size_t)(b * NPOS + mB) * NC + 8 * g;
  const bf16x8 kb0 = *(const bf16x8*)(kbA);
  const bf16x8 kb1 = *(const bf16x8*)(kbA + 32);
  const bf16x8 kb2 = *(const bf16x8*)(kbB);
  const bf16x8 kb3 = *(const bf16x8*)(kbB + 32);

  const char* qb  = (const char*)(qT + (size_t)b * NPOS * NC);
  const char* vbb = (const char*)(vb + (size_t)b * NC * NPOS);

  // staging geometry: thread t writes 16B at LDS byte t*16 = (row=t>>3, swz col (t&7)*16)
  const int srow = tid >> 3;
  const int slc  = ((tid & 7) * 16) ^ ((srow & 7) << 4);  // inverse-swizzled src col
  const char* qsrc0 = qb + (size_t)srow * 128 + slc;          // + n0*128
  const char* vsrc0 = vbb + (size_t)srow * (NPOS * 2) + slc;  // + n0*2
  const int ldsoff = w * 512;  // shorts; wave-uniform base for global_load_lds

  f32x4 accA[4] = {{0,0,0,0},{0,0,0,0},{0,0,0,0},{0,0,0,0}};
  f32x4 accB[4] = {{0,0,0,0},{0,0,0,0},{0,0,0,0},{0,0,0,0}};
  float lsumA = 0.f, lsumB = 0.f;

  const int nbeg = z * NCHUNK;
  const int iters = NCHUNK >> 6;  // 32, even for all z

  // prologue: stage buffer 0
  gload_lds16(qsrc0 + (size_t)nbeg * 128, &qs_[0][ldsoff]);
  gload_lds16(vsrc0 + (size_t)nbeg * 2,   &vs_[0][ldsoff]);

  const int swz = (lm & 7) << 4;  // read-side swizzle

  int cur = 0;
  for (int t = 0; t < iters; ++t) {
    const int n0 = nbeg + 64 * t;
    // barrier A: everyone finished reading buf cur^1 (iter t-1) -> safe to overwrite
    __builtin_amdgcn_s_barrier();
    if (t + 1 < iters) {
      gload_lds16(qsrc0 + (size_t)(n0 + 64) * 128, &qs_[cur ^ 1][ldsoff]);
      gload_lds16(vsrc0 + (size_t)(n0 + 64) * 2,   &vs_[cur ^ 1][ldsoff]);
      asm volatile("s_waitcnt vmcnt(2)" ::: "memory");  // stage(t) done; t+1 in flight
    } else {
      asm volatile("s_waitcnt vmcnt(0)" ::: "memory");
    }
    // barrier B: all waves' stage(t) complete -> tile readable
    __builtin_amdgcn_s_barrier();
    __builtin_amdgcn_sched_barrier(0);

    const unsigned short* qt = qs_[cur];
    const unsigned short* vt = vs_[cur];

    // ======== pass A: QK -> SM -> PV for column set A ========
    {
      f32x4 s[4];
      __builtin_amdgcn_s_setprio(1);
#pragma unroll
      for (int sub = 0; sub < 4; ++sub) {
        const int nl = 16 * sub + lm;
        bf16x8 qa0 = *(const bf16x8*)(qt + nl * 64 + (((16 * g) ^ swz) >> 1));
        bf16x8 qa1 = *(const bf16x8*)(qt + nl * 64 + (((64 + 16 * g) ^ swz) >> 1));
        f32x4 zz = {0, 0, 0, 0};
        zz = __builtin_amdgcn_mfma_f32_16x16x32_bf16(qa0, kb0, zz, 0, 0, 0);
        zz = __builtin_amdgcn_mfma_f32_16x16x32_bf16(qa1, kb1, zz, 0, 0, 0);
        s[sub] = zz;
      }
      __builtin_amdgcn_s_setprio(0);
#pragma unroll
      for (int sub = 0; sub < 4; ++sub) {
        float p0 = EXP2F(s[sub][0]);
        float p1 = EXP2F(s[sub][1]);
        float p2 = EXP2F(s[sub][2]);
        float p3 = EXP2F(s[sub][3]);
        lsumA += (p0 + p1) + (p2 + p3);
        bf16x4 pk;
        pk[0] = (__bf16)p0; pk[1] = (__bf16)p1;
        pk[2] = (__bf16)p2; pk[3] = (__bf16)p3;
        *(bf16x4*)&pT[w][lm][16 * sub + 4 * g] = pk;
      }
      __builtin_amdgcn_s_setprio(1);
#pragma unroll
      for (int ks = 0; ks < 2; ++ks) {
        bf16x8 pb = *(const bf16x8*)&pT[w][lm][8 * g + 32 * ks];
#pragma unroll
        for (int cs = 0; cs < 4; ++cs) {
          const int vr = 16 * cs + lm;
          bf16x8 va = *(const bf16x8*)(vt + vr * 64 + (((16 * g + 64 * ks) ^ swz) >> 1));
          accA[cs] = __builtin_amdgcn_mfma_f32_16x16x32_bf16(va, pb, accA[cs], 0, 0, 0);
        }
      }
      __builtin_amdgcn_s_setprio(0);
    }

    // ======== pass B: QK -> SM -> PV for column set B ========
    {
      f32x4 s[4];
      __builtin_amdgcn_s_setprio(1);
#pragma unroll
      for (int sub = 0; sub < 4; ++sub) {
        const int nl = 16 * sub + lm;
        bf16x8 qa0 = *(const bf16x8*)(qt + nl * 64 + (((16 * g) ^ swz) >> 1));
        bf16x8 qa1 = *(const bf16x8*)(qt + nl * 64 + (((64 + 16 * g) ^ swz) >> 1));
        f32x4 zz = {0, 0, 0, 0};
        zz = __builtin_amdgcn_mfma_f32_16x16x32_bf16(qa0, kb2, zz, 0, 0, 0);
        zz = __builtin_amdgcn_mfma_f32_16x16x32_bf16(qa1, kb3, zz, 0, 0, 0);
        s[sub] = zz;
      }
      __builtin_amdgcn_s_setprio(0);
#pragma unroll
      for (int sub = 0; sub < 4; ++sub) {
        float p0 = EXP2F(s[sub][0]);
        float p1 = EXP2F(s[sub][1]);
        float p2 = EXP2F(s[sub][2]);
        float p3 = EXP2F(s[sub][3]);
        lsumB += (p0 + p1) + (p2 + p3);
        bf16x4 pk;
        pk[0] = (__bf16)p0; pk[1] = (__bf16)p1;
        pk[2] = (__bf16)p2; pk[3] = (__bf16)p3;
        *(bf16x4*)&pT[w][lm][16 * sub + 4 * g] = pk;
      }
      __builtin_amdgcn_s_setprio(1);
#pragma unroll
      for (int ks = 0; ks < 2; ++ks) {
        bf16x8 pb = *(const bf16x8*)&pT[w][lm][8 * g + 32 * ks];
#pragma unroll
        for (int cs = 0; cs < 4; ++cs) {
          const int vr = 16 * cs + lm;
          bf16x8 va = *(const bf16x8*)(vt + vr * 64 + (((16 * g + 64 * ks) ^ swz) >> 1));
          accB[cs] = __builtin_amdgcn_mfma_f32_16x16x32_bf16(va, pb, accB[cs], 0, 0, 0);
        }
      }
      __builtin_amdgcn_s_setprio(0);
    }
    cur ^= 1;
  }

  lsumA += __shfl_xor(lsumA, 16);
  lsumA += __shfl_xor(lsumA, 32);
  lsumB += __shfl_xor(lsumB, 16);
  lsumB += __shfl_xor(lsumB, 32);
  if (l < 16) {
    plsum[((size_t)(z * NB + b) << 13) + mA] = lsumA;
    plsum[((size_t)(z * NB + b) << 13) + mB] = lsumB;
  }

  float* po = pav + ((size_t)((z * NB + b) * NC) << 13);
#pragma unroll
  for (int cs = 0; cs < 4; ++cs) {
#pragma unroll
    for (int r = 0; r < 4; ++r) {
      const int c = 16 * cs + 4 * g + r;
      po[((size_t)c << 13) + mA] = accA[cs][r];
      po[((size_t)c << 13) + mB] = accB[cs][r];
    }
  }
}

// Stage 3: combine partials, normalize, epilogue.
__global__ __launch_bounds__(256) void reduce_kernel(
    const float* __restrict__ pav, const float* __restrict__ plsum,
    const float* __restrict__ vf, const float* __restrict__ gamma_p,
    float* __restrict__ out)
{
  const size_t base = ((size_t)blockIdx.x * 256 + threadIdx.x) * 4;
  const int m = (int)(base & (NPOS - 1));
  const int bc = (int)(base >> 13);       // b*64 + c
  const int b = bc >> 6;

  float4 s = {0, 0, 0, 0};
  float4 L = {0, 0, 0, 0};
#pragma unroll
  for (int zz = 0; zz < NSPLIT; ++zz) {
    const float4 a = *(const float4*)(pav + (((size_t)(zz * NB * NC + bc)) << 13) + m);
    s.x += a.x; s.y += a.y; s.z += a.z; s.w += a.w;
    const float4 q = *(const float4*)(plsum + (((size_t)(zz * NB + b)) << 13) + m);
    L.x += q.x; L.y += q.y; L.z += q.z; L.w += q.w;
  }
  const float gmv = gamma_p[0];
  const float4 v4 = *(const float4*)(vf + base);
  float4 o;
  o.x = gmv * s.x / L.x + v4.x;
  o.y = gmv * s.y / L.y + v4.y;
  o.z = gmv * s.z / L.z + v4.z;
  o.w = gmv * s.w / L.w + v4.w;
  *(float4*)(out + base) = o;
}

extern "C" void kernel_launch(void* const* d_in, const int* in_sizes, int n_in,
                              void* d_out, int out_size, void* d_ws, size_t ws_size,
                              hipStream_t stream) {
  const float* xq = (const float*)d_in[0];
  const float* xk = (const float*)d_in[1];
  const float* xv = (const float*)d_in[2];
  const float* Wq = (const float*)d_in[3];
  const float* bq = (const float*)d_in[4];
  const float* Wk = (const float*)d_in[5];
  const float* bk = (const float*)d_in[6];
  const float* Wv = (const float*)d_in[7];
  const float* bv = (const float*)d_in[8];
  const float* gm = (const float*)d_in[9];
  float* out = (float*)d_out;

  // ws: qT(4MB) | kT(4MB) | v_bf16(4MB) | v_f32(8MB) | pav(32MB) | plsum(512KB)
  unsigned short* qT   = (unsigned short*)d_ws;
  unsigned short* kT   = qT + (size_t)NB * NPOS * NC;
  unsigned short* vbuf = kT + (size_t)NB * NPOS * NC;
  float* vf    = (float*)(vbuf + (size_t)NB * NPOS * NC);
  float* pav   = vf + (size_t)NB * NC * NPOS;
  float* plsum = pav + (size_t)NSPLIT * NB * NC * NPOS;

  hipLaunchKernelGGL(proj_kernel, dim3(64, 4, 3), dim3(256), 0, stream,
                     xq, xk, xv, Wq, bq, Wk, bk, Wv, bv, qT, kT, vbuf, vf);
  hipLaunchKernelGGL(attn_partial, dim3(NPOS / 256, NB, NSPLIT), dim3(512), 0, stream,
                     qT, kT, vbuf, pav, plsum);
  hipLaunchKernelGGL(reduce_kernel, dim3(2048), dim3(256), 0, stream,
                     pav, plsum, vf, gm, out);
}